// Round 9
// baseline (270.477 us; speedup 1.0000x reference)
//
#include <hip/hip_runtime.h>
#include <math.h>

#define BATCH 1024
#define VOCAB 100000
#define KDIM  300
#define TOPK  10

#define NKB    10            // K blocks of 32 (K padded 300 -> 320)
#define NCB_B  6272          // vocab col-blocks of 16 (98 chunks * 64), pad to 100352
#define NCB_A  64            // 1024 rows / 16
#define NCHUNK 98            // col chunks of 1024
#define NCHPAD 104           // padded to multiple of 8 for XCD swizzle
#define NWIN   8             // 128-col windows per chunk
#define NSTEP  (NWIN*NKB)    // 80 pipeline steps per block
#define CSLOT  32            // candidate u32s per (row, chunk): 2 wn * 4 lk * depth 4
#define NCAND  (NCHUNK*CSLOT) // 3136 per row (quad candidates)
#define NKF    24            // final quad rescore set -> 96 cols
#define NDOT   (NKF*4)       // 96 exact dots per row

typedef __attribute__((ext_vector_type(8))) short bf16x8;
typedef __attribute__((ext_vector_type(4))) float f32x4;

#define GL2LDS(gsrc, ldst)                                                    \
    __builtin_amdgcn_global_load_lds(                                         \
        (const __attribute__((address_space(1))) void*)(gsrc),                \
        (__attribute__((address_space(3))) void*)(ldst), 16, 0, 0)

__device__ __forceinline__ ushort f2bf(float f) {
    union { float f; unsigned u; } v; v.f = f;
    unsigned r = v.u + 0x7FFFu + ((v.u >> 16) & 1u);  // RNE
    return (ushort)(r >> 16);
}

// depth-4 descending insert, SIGNED keys (sentinel 0; negatives never insert)
__device__ __forceinline__ void ins4(int (&l)[4], int e) {
    if (e <= l[3]) return;
    bool g0 = e > l[0], g1 = e > l[1], g2 = e > l[2];
    l[3] = g2 ? l[2] : e;
    l[2] = g2 ? (g1 ? l[1] : e) : l[2];
    l[1] = g1 ? (g0 ? l[0] : e) : l[1];
    l[0] = g0 ? e : l[0];
}

// descending (key,val) insert, depth N, SIGNED keys, fully unrolled
template<int N>
__device__ __forceinline__ void pins(int (&ks)[N], int (&vs)[N], int k, int v) {
    if (k <= ks[N-1]) return;
    #pragma unroll
    for (int p = N-1; p >= 0; --p) {
        bool gt  = k > ks[p];
        bool gtp = (p > 0) ? (k > ks[p-1]) : false;
        int nk = gt ? (gtp ? ks[p-1] : k) : ks[p];
        int nv = gt ? (gtp ? vs[p-1] : v) : vs[p];
        ks[p] = nk; vs[p] = nv;
    }
}

// ---------------------------------------------------------------------------
// Kernel 1 (round 9 rewrite): LDS-free fragment packer. One wave per col-block,
// loop over kb. Lane l holds row (l&15), k = kb*32 + (l>>4)*8 + j — exactly the
// MFMA fragment element [r2-verified], so it loads 2 float4 from weight and
// packs 4 dwords in-register. No barriers; every weight element read once.
//   B frag (kb, cb):   ws_b[((kb*NCB_B + cb)*64 + lane)*8 .. +7]
//   A frag (kb, rb16): ws_a[((kb*64   + rb16)*64 + lane)*8 .. +7]
// ---------------------------------------------------------------------------
__global__ __launch_bounds__(256)
void convert_frags(const int* __restrict__ wordid, const float* __restrict__ weight,
                   ushort* __restrict__ ws_b, ushort* __restrict__ ws_a, int nb4)
{
    const int t   = threadIdx.x;
    const int w   = t >> 6, l = t & 63;
    const int bid = blockIdx.x;
    const bool is_a = (bid >= nb4);
    const int cb  = (is_a ? (bid - nb4) : bid) * 4 + w;
    ushort* dst = is_a ? ws_a : ws_b;
    const int kstride = is_a ? 64 : NCB_B;

    const int r16  = l & 15;
    const int ksub = (l >> 4) * 8;

    const int row = is_a ? wordid[cb*16 + r16] : (cb*16 + r16);
    const bool vr = (row < VOCAB);
    const float* src = weight + (size_t)(vr ? row : 0) * KDIM;

    #pragma unroll
    for (int kb = 0; kb < NKB; ++kb) {
        const int k0 = kb*32 + ksub;
        float4 a = make_float4(0.f,0.f,0.f,0.f);
        float4 b = make_float4(0.f,0.f,0.f,0.f);
        if (vr) {
            if (k0 + 8 <= KDIM) {
                a = *reinterpret_cast<const float4*>(src + k0);
                b = *reinterpret_cast<const float4*>(src + k0 + 4);
            } else if (k0 + 4 <= KDIM) {          // k0 == 296: half valid
                a = *reinterpret_cast<const float4*>(src + k0);
            }                                      // k0 >= 304: zero pad
        }
        uint4 o;
        o.x = (unsigned)f2bf(a.x) | ((unsigned)f2bf(a.y) << 16);
        o.y = (unsigned)f2bf(a.z) | ((unsigned)f2bf(a.w) << 16);
        o.z = (unsigned)f2bf(b.x) | ((unsigned)f2bf(b.y) << 16);
        o.w = (unsigned)f2bf(b.z) | ((unsigned)f2bf(b.w) << 16);
        *reinterpret_cast<uint4*>(&dst[((size_t)kb*kstride + cb)*512 + (size_t)l*8]) = o;
    }
}

// ---------------------------------------------------------------------------
// Kernel 2: MFMA pipeline + fused quad-max candidates, XCD-residency swizzle.
// Round 9: depth-3 prefetch — 4 LDS buffers (64 KB), stage batch s+3 right
// after the barrier, steady-state wait vmcnt(8) (tail: 4, then 0). Gives
// ~3 step-times of load slack to cover L3/HBM latency. 2 blocks/CU.
// ---------------------------------------------------------------------------
__global__ __launch_bounds__(256, 2)
void sim_gemm(const ushort* __restrict__ ws_a, const ushort* __restrict__ ws_b,
              unsigned* __restrict__ cand)
{
    __shared__ __align__(16) ushort Abuf[4][8*512];   // 4 x 8 KB
    __shared__ __align__(16) ushort Bbuf[4][8*512];

    const int id    = blockIdx.x;
    const int chunk = (id & 7) + ((id >> 6) << 3);   // XCD-residency swizzle
    const int rbid  = (id >> 3) & 7;
    if (chunk >= NCHUNK) return;

    const int t     = threadIdx.x;
    const int wid   = t >> 6, lane = t & 63;
    const int wm    = wid >> 1, wn = wid & 1;
    const int l16   = lane & 15, lk = lane >> 4;
    const int rb16b = rbid * 8;

    int ps[4][4];
    #pragma unroll
    for (int m = 0; m < 4; ++m)
        #pragma unroll
        for (int e = 0; e < 4; ++e) ps[m][e] = 0;

    const int f = wid * 2;
    const ushort* abase = ws_a + ((size_t)(rb16b + f)*512) + (size_t)lane*8;
    const ushort* bbase = ws_b + ((size_t)(chunk*64 + f)*512) + (size_t)lane*8;

    auto stage = [&](int sit, int skb, int buf) {
        const ushort* pa = abase + (size_t)skb*(64*512);
        GL2LDS(pa,       &Abuf[buf][f*512]);
        GL2LDS(pa + 512, &Abuf[buf][(f+1)*512]);
        const ushort* pb = bbase + (size_t)skb*((size_t)NCB_B*512) + (size_t)sit*(8*512);
        GL2LDS(pb,       &Bbuf[buf][f*512]);
        GL2LDS(pb + 512, &Bbuf[buf][(f+1)*512]);
    };

    stage(0, 0, 0);
    stage(0, 1, 1);
    stage(0, 2, 2);
    int nit = 0, nkb = 3;                // next batch to stage (linear idx 3)
    int cur = 0;                         // s % 4
    int s = 0;
    const int qbase = wn*16 + lk;

    for (int it = 0; it < NWIN; ++it) {
        f32x4 acc[4][4] = {};

        for (int kb = 0; kb < NKB; ++kb, ++s) {
            // drain exactly batch s (oldest 4 loads): 3 batches may stay in flight
            if (s < NSTEP-2)       { asm volatile("s_waitcnt vmcnt(8)" ::: "memory"); }
            else if (s == NSTEP-2) { asm volatile("s_waitcnt vmcnt(4)" ::: "memory"); }
            else                   { asm volatile("s_waitcnt vmcnt(0)" ::: "memory"); }
            __builtin_amdgcn_s_barrier();
            asm volatile("" ::: "memory");

            // stage batch s+3 into buf (s+3)%4 = (s-1)%4 (read finished at s-1)
            if (s <= NSTEP-4) {
                stage(nit, nkb, (cur + 3) & 3);
                ++nkb; if (nkb == NKB) { nkb = 0; ++nit; }
            }

            bf16x8 af[4], bfr[4];
            #pragma unroll
            for (int m = 0; m < 4; ++m)
                af[m] = *reinterpret_cast<const bf16x8*>(&Abuf[cur][(wm*4+m)*512 + lane*8]);
            #pragma unroll
            for (int n = 0; n < 4; ++n)
                bfr[n] = *reinterpret_cast<const bf16x8*>(&Bbuf[cur][(wn*4+n)*512 + lane*8]);

            #pragma unroll
            for (int m = 0; m < 4; ++m)
                #pragma unroll
                for (int n = 0; n < 4; ++n)
                    acc[m][n] = __builtin_amdgcn_mfma_f32_16x16x32_bf16(bfr[n], af[m], acc[m][n], 0, 0, 0);

            cur = (cur + 1) & 3;
        }

        #pragma unroll
        for (int m = 0; m < 4; ++m)
            #pragma unroll
            for (int n = 0; n < 4; ++n) {
                float qm = fmaxf(fmaxf(acc[m][n][0], acc[m][n][1]),
                                 fmaxf(acc[m][n][2], acc[m][n][3]));
                int key = (int)((__float_as_uint(qm) & 0xFFFF0000u)
                                | (unsigned)(it*32 + n*4 + qbase));
                ins4(ps[m], key);
            }
    }

    #pragma unroll
    for (int m = 0; m < 4; ++m) {
        int row = rb16b*16 + wm*64 + m*16 + l16;
        size_t base = (size_t)row*NCAND + chunk*CSLOT + wn*16 + lk*4;
        *reinterpret_cast<uint4*>(&cand[base]) =
            make_uint4((unsigned)ps[m][0], (unsigned)ps[m][1],
                       (unsigned)ps[m][2], (unsigned)ps[m][3]);
    }
}

// ---------------------------------------------------------------------------
// Kernel 3a: per row, hierarchical merge 3136 quad candidates -> top-24 quads.
// [unchanged]
// ---------------------------------------------------------------------------
__global__ __launch_bounds__(128, 4)
void merge_topq(const unsigned* __restrict__ cand, int* __restrict__ quads)
{
    __shared__ int Ks[128*8];
    __shared__ int Vs[128*8];
    __shared__ int K24[16*NKF];
    __shared__ int V24[16*NKF];

    const int row  = blockIdx.x;
    const int lane = threadIdx.x;

    int ks[8]; int vs[8];
    #pragma unroll
    for (int i = 0; i < 8; ++i) { ks[i] = 0; vs[i] = 0; }

    const unsigned* rc = cand + (size_t)row*NCAND;
    for (int c = lane; c < NCAND; c += 128) {
        int e  = (int)rc[c];
        int gq = ((c >> 5) << 8) | (e & 255);   // chunk*256 + local quad
        pins<8>(ks, vs, e, gq);
    }
    #pragma unroll
    for (int i = 0; i < 8; ++i) { Ks[lane*8 + i] = ks[i]; Vs[lane*8 + i] = vs[i]; }
    __syncthreads();

    if (lane < 16) {
        int gk[NKF]; int gv[NKF];
        #pragma unroll
        for (int i = 0; i < NKF; ++i) { gk[i] = 0; gv[i] = 0; }
        for (int l = lane*8; l < lane*8 + 8; ++l) {
            for (int i = 0; i < 8; ++i) {          // lane lists sorted desc
                int e = Ks[l*8 + i];
                if (e <= gk[NKF-1]) break;
                pins<NKF>(gk, gv, e, Vs[l*8 + i]);
            }
        }
        #pragma unroll
        for (int i = 0; i < NKF; ++i) { K24[lane*NKF + i] = gk[i]; V24[lane*NKF + i] = gv[i]; }
    }
    __syncthreads();

    if (lane == 0) {
        int gk[NKF]; int gv[NKF];
        #pragma unroll
        for (int i = 0; i < NKF; ++i) { gk[i] = 0; gv[i] = 0; }
        for (int l = 0; l < 16; ++l) {
            for (int i = 0; i < NKF; ++i) {
                int e = K24[l*NKF + i];
                if (e <= gk[NKF-1]) break;
                pins<NKF>(gk, gv, e, V24[l*NKF + i]);
            }
        }
        #pragma unroll
        for (int i = 0; i < NKF; ++i) quads[row*NKF + i] = gv[i];
    }
}

// ---------------------------------------------------------------------------
// Kernel 3b: dense exact rescore. One 16-lane group per dot; 98304 dots.
// [unchanged]
// ---------------------------------------------------------------------------
__global__ __launch_bounds__(256, 8)
void rescore_exact(const int* __restrict__ quads, const int* __restrict__ wordid,
                   const float* __restrict__ weight, double* __restrict__ scores)
{
    const int g = (blockIdx.x * 256 + threadIdx.x) >> 4;   // dot id
    const int l = threadIdx.x & 15;
    const int row = g / NDOT;
    const int ci  = g - row * NDOT;

    const int q   = quads[row*NKF + (ci >> 2)];
    const int col = q*4 + (ci & 3);
    const bool valid = (col < VOCAB);
    const int col_eff = valid ? col : 0;

    const float* qr = weight + (size_t)wordid[row]*KDIM;
    const float* wr = weight + (size_t)col_eff*KDIM;

    double a0 = 0.0, a1 = 0.0;
    #pragma unroll
    for (int k = 0; k < 4; ++k) {
        int sl = (l + 16*k) * 4;
        float4 qa = *reinterpret_cast<const float4*>(qr + sl);
        float4 wb = *reinterpret_cast<const float4*>(wr + sl);
        a0 += (double)qa.x * wb.x + (double)qa.z * wb.z;
        a1 += (double)qa.y * wb.y + (double)qa.w * wb.w;
    }
    if (l < 11) {
        int sl = (l + 64) * 4;
        float4 qa = *reinterpret_cast<const float4*>(qr + sl);
        float4 wb = *reinterpret_cast<const float4*>(wr + sl);
        a0 += (double)qa.x * wb.x + (double)qa.z * wb.z;
        a1 += (double)qa.y * wb.y + (double)qa.w * wb.w;
    }
    double a = a0 + a1;
    #pragma unroll
    for (int m = 1; m < 16; m <<= 1) a += __shfl_xor(a, m);

    if (l == 0) scores[g] = valid ? a : -1e300;
}

// ---------------------------------------------------------------------------
// Kernel 3c: per row, wave-parallel top-11 of the 96 exact scores.
// [unchanged]
// ---------------------------------------------------------------------------
__global__ __launch_bounds__(64, 8)
void final_select(const double* __restrict__ scores, const int* __restrict__ quads,
                  float* __restrict__ out)
{
    const int row  = blockIdx.x;
    const int lane = threadIdx.x;

    double v0 = -INFINITY, v1 = -INFINITY;
    int    c0 = 0x7fffffff, c1 = 0x7fffffff;
    if (lane < NDOT/2) {
        int i0 = lane*2, i1 = lane*2 + 1;
        v0 = scores[(size_t)row*NDOT + i0];
        v1 = scores[(size_t)row*NDOT + i1];
        c0 = quads[row*NKF + (i0 >> 2)]*4 + (i0 & 3);
        c1 = quads[row*NKF + (i1 >> 2)]*4 + (i1 & 3);
    }

    for (int kk = 0; kk < TOPK + 1; ++kk) {
        bool sel = (v0 > v1) || (v0 == v1 && c0 < c1);
        double bv = sel ? v0 : v1;
        int    bc = sel ? c0 : c1;
        #pragma unroll
        for (int m = 1; m < 64; m <<= 1) {
            double ov = __shfl_xor(bv, m);
            int    oc = __shfl_xor(bc, m);
            if (ov > bv || (ov == bv && oc < bc)) { bv = ov; bc = oc; }
        }
        if (kk >= 1 && lane == 0) {
            out[(size_t)row*TOPK + (kk-1)] = (float)bv;
            out[(size_t)BATCH*TOPK + (size_t)row*TOPK + (kk-1)] = (float)bc;
        }
        if (c0 == bc) v0 = -INFINITY;
        if (c1 == bc) v1 = -INFINITY;
    }
}

extern "C" void kernel_launch(void* const* d_in, const int* in_sizes, int n_in,
                              void* d_out, int out_size, void* d_ws, size_t ws_size,
                              hipStream_t stream) {
    const int*   wordid = (const int*)d_in[0];
    const float* weight = (const float*)d_in[1];
    float* out = (float*)d_out;

    const size_t SZ_B = (size_t)NCB_B * NKB * 64 * 16;   // 64,225,280 B
    const size_t SZ_A = (size_t)NCB_A * NKB * 64 * 16;   //    655,360 B

    char* p = (char*)d_ws;
    ushort*   ws_b = (ushort*)p;  p += SZ_B;
    ushort*   ws_a = (ushort*)p;  p += SZ_A;
    unsigned* cand = (unsigned*)p;

    int*    quads  = (int*)ws_a;      // ws_a dead after sim_gemm
    double* scores = (double*)cand;   // cand dead after merge_topq

    convert_frags<<<NCB_B/4 + NCB_A/4, 256, 0, stream>>>(wordid, weight, ws_b, ws_a, NCB_B/4);
    sim_gemm<<<NCHPAD*8, 256, 0, stream>>>(ws_a, ws_b, cand);
    merge_topq<<<BATCH, 128, 0, stream>>>(cand, quads);
    rescore_exact<<<(BATCH*NDOT)/16, 256, 0, stream>>>(quads, wordid, weight, scores);
    final_select<<<BATCH, 64, 0, stream>>>(scores, quads, out);
}

// Round 10
// 262.436 us; speedup vs baseline: 1.0306x; 1.0306x over previous
//
#include <hip/hip_runtime.h>
#include <math.h>

#define BATCH 1024
#define VOCAB 100000
#define KDIM  300
#define TOPK  10

#define NKB    10            // K blocks of 32 (K padded 300 -> 320)
#define NCB_B  6272          // vocab col-blocks of 16 (98 chunks * 64), pad to 100352
#define NCB_A  64            // 1024 rows / 16
#define NCHUNK 98            // col chunks of 1024
#define NCHPAD 104           // padded to multiple of 8 for XCD swizzle
#define NWIN   8             // 128-col windows per chunk
#define NSTEP  (NWIN*NKB)    // 80 pipeline steps per block
#define CSLOT  32            // candidate u32s per (row, chunk): 2 wn * 4 lk * depth 4
#define NCAND  (NCHUNK*CSLOT) // 3136 per row (quad candidates)
#define NKF    24            // final quad rescore set -> 96 cols
#define NDOT   (NKF*4)       // 96 exact dots per row

typedef __attribute__((ext_vector_type(8))) short bf16x8;
typedef __attribute__((ext_vector_type(4))) float f32x4;

#define GL2LDS(gsrc, ldst)                                                    \
    __builtin_amdgcn_global_load_lds(                                         \
        (const __attribute__((address_space(1))) void*)(gsrc),                \
        (__attribute__((address_space(3))) void*)(ldst), 16, 0, 0)

__device__ __forceinline__ ushort f2bf(float f) {
    union { float f; unsigned u; } v; v.f = f;
    unsigned r = v.u + 0x7FFFu + ((v.u >> 16) & 1u);  // RNE
    return (ushort)(r >> 16);
}

// depth-4 descending insert, SIGNED keys (sentinel 0; negatives never insert)
__device__ __forceinline__ void ins4(int (&l)[4], int e) {
    if (e <= l[3]) return;
    bool g0 = e > l[0], g1 = e > l[1], g2 = e > l[2];
    l[3] = g2 ? l[2] : e;
    l[2] = g2 ? (g1 ? l[1] : e) : l[2];
    l[1] = g1 ? (g0 ? l[0] : e) : l[1];
    l[0] = g0 ? e : l[0];
}

// descending (key,val) insert, depth N, SIGNED keys, fully unrolled
template<int N>
__device__ __forceinline__ void pins(int (&ks)[N], int (&vs)[N], int k, int v) {
    if (k <= ks[N-1]) return;
    #pragma unroll
    for (int p = N-1; p >= 0; --p) {
        bool gt  = k > ks[p];
        bool gtp = (p > 0) ? (k > ks[p-1]) : false;
        int nk = gt ? (gtp ? ks[p-1] : k) : ks[p];
        int nv = gt ? (gtp ? vs[p-1] : v) : vs[p];
        ks[p] = nk; vs[p] = nv;
    }
}

// ---------------------------------------------------------------------------
// Kernel 1: LDS-free fragment packer. [unchanged from round 9]
//   B frag (kb, cb):   ws_b[((kb*NCB_B + cb)*64 + lane)*8 .. +7]
//   A frag (kb, rb16): ws_a[((kb*64   + rb16)*64 + lane)*8 .. +7]
// ---------------------------------------------------------------------------
__global__ __launch_bounds__(256)
void convert_frags(const int* __restrict__ wordid, const float* __restrict__ weight,
                   ushort* __restrict__ ws_b, ushort* __restrict__ ws_a, int nb4)
{
    const int t   = threadIdx.x;
    const int w   = t >> 6, l = t & 63;
    const int bid = blockIdx.x;
    const bool is_a = (bid >= nb4);
    const int cb  = (is_a ? (bid - nb4) : bid) * 4 + w;
    ushort* dst = is_a ? ws_a : ws_b;
    const int kstride = is_a ? 64 : NCB_B;

    const int r16  = l & 15;
    const int ksub = (l >> 4) * 8;

    const int row = is_a ? wordid[cb*16 + r16] : (cb*16 + r16);
    const bool vr = (row < VOCAB);
    const float* src = weight + (size_t)(vr ? row : 0) * KDIM;

    #pragma unroll
    for (int kb = 0; kb < NKB; ++kb) {
        const int k0 = kb*32 + ksub;
        float4 a = make_float4(0.f,0.f,0.f,0.f);
        float4 b = make_float4(0.f,0.f,0.f,0.f);
        if (vr) {
            if (k0 + 8 <= KDIM) {
                a = *reinterpret_cast<const float4*>(src + k0);
                b = *reinterpret_cast<const float4*>(src + k0 + 4);
            } else if (k0 + 4 <= KDIM) {          // k0 == 296: half valid
                a = *reinterpret_cast<const float4*>(src + k0);
            }                                      // k0 >= 304: zero pad
        }
        uint4 o;
        o.x = (unsigned)f2bf(a.x) | ((unsigned)f2bf(a.y) << 16);
        o.y = (unsigned)f2bf(a.z) | ((unsigned)f2bf(a.w) << 16);
        o.z = (unsigned)f2bf(b.x) | ((unsigned)f2bf(b.y) << 16);
        o.w = (unsigned)f2bf(b.z) | ((unsigned)f2bf(b.w) << 16);
        *reinterpret_cast<uint4*>(&dst[((size_t)kb*kstride + cb)*512 + (size_t)l*8]) = o;
    }
}

// ---------------------------------------------------------------------------
// Kernel 2 (round 10): single-round 2-phase pipeline.
// 2 LDS buffers (32 KB) + __launch_bounds__(256,4) -> 1024 co-residency slots
// >= 832 blocks: ALL blocks run in one round (round-9 analysis showed the
// 48 KB/3-per-CU config forced a 2nd dispatch round = 2x kernel time).
// T3 minimal 2-phase per step: issue STAGE(s+1, buf^1) first, then
// ds_read+MFMA from buf, then one vmcnt(0)+s_barrier. Per-wave stage-drain
// stalls are hidden by 16 waves/SIMD of TLP.
// ---------------------------------------------------------------------------
__global__ __launch_bounds__(256, 4)
void sim_gemm(const ushort* __restrict__ ws_a, const ushort* __restrict__ ws_b,
              unsigned* __restrict__ cand)
{
    __shared__ __align__(16) ushort Abuf[2][8*512];   // 2 x 8 KB
    __shared__ __align__(16) ushort Bbuf[2][8*512];

    const int id    = blockIdx.x;
    const int chunk = (id & 7) + ((id >> 6) << 3);   // XCD-residency swizzle
    const int rbid  = (id >> 3) & 7;
    if (chunk >= NCHUNK) return;

    const int t     = threadIdx.x;
    const int wid   = t >> 6, lane = t & 63;
    const int wm    = wid >> 1, wn = wid & 1;
    const int l16   = lane & 15, lk = lane >> 4;
    const int rb16b = rbid * 8;

    int ps[4][4];
    #pragma unroll
    for (int m = 0; m < 4; ++m)
        #pragma unroll
        for (int e = 0; e < 4; ++e) ps[m][e] = 0;

    const int f = wid * 2;
    const ushort* abase = ws_a + ((size_t)(rb16b + f)*512) + (size_t)lane*8;
    const ushort* bbase = ws_b + ((size_t)(chunk*64 + f)*512) + (size_t)lane*8;

    auto stage = [&](int sit, int skb, int buf) {
        const ushort* pa = abase + (size_t)skb*(64*512);
        GL2LDS(pa,       &Abuf[buf][f*512]);
        GL2LDS(pa + 512, &Abuf[buf][(f+1)*512]);
        const ushort* pb = bbase + (size_t)skb*((size_t)NCB_B*512) + (size_t)sit*(8*512);
        GL2LDS(pb,       &Bbuf[buf][f*512]);
        GL2LDS(pb + 512, &Bbuf[buf][(f+1)*512]);
    };

    // prologue: fill buf 0, drain, barrier
    stage(0, 0, 0);
    asm volatile("s_waitcnt vmcnt(0)" ::: "memory");
    __builtin_amdgcn_s_barrier();
    asm volatile("" ::: "memory");

    int nit = 0, nkb = 1;                // next batch (it,kb) to stage
    int cur = 0;
    int s = 0;
    const int qbase = wn*16 + lk;

    for (int it = 0; it < NWIN; ++it) {
        f32x4 acc[4][4] = {};

        for (int kb = 0; kb < NKB; ++kb, ++s) {
            // phase A: issue next step's staging into the other buffer
            if (s < NSTEP-1) {
                stage(nit, nkb, cur ^ 1);
                ++nkb; if (nkb == NKB) { nkb = 0; ++nit; }
            }

            // phase B: compute current buffer (compiler inserts lgkmcnt
            // before MFMA for the ds_read deps; all reads consumed by MFMA
            // before the barrier, so buffer reuse next step is safe)
            bf16x8 af[4], bfr[4];
            #pragma unroll
            for (int m = 0; m < 4; ++m)
                af[m] = *reinterpret_cast<const bf16x8*>(&Abuf[cur][(wm*4+m)*512 + lane*8]);
            #pragma unroll
            for (int n = 0; n < 4; ++n)
                bfr[n] = *reinterpret_cast<const bf16x8*>(&Bbuf[cur][(wn*4+n)*512 + lane*8]);

            #pragma unroll
            for (int m = 0; m < 4; ++m)
                #pragma unroll
                for (int n = 0; n < 4; ++n)
                    acc[m][n] = __builtin_amdgcn_mfma_f32_16x16x32_bf16(bfr[n], af[m], acc[m][n], 0, 0, 0);

            // phase C: one drain+barrier per step -> next buffer ready
            asm volatile("s_waitcnt vmcnt(0)" ::: "memory");
            __builtin_amdgcn_s_barrier();
            asm volatile("" ::: "memory");
            cur ^= 1;
        }

        // quad scan: one insert per (m,n) quad of 4 consecutive cols
        #pragma unroll
        for (int m = 0; m < 4; ++m)
            #pragma unroll
            for (int n = 0; n < 4; ++n) {
                float qm = fmaxf(fmaxf(acc[m][n][0], acc[m][n][1]),
                                 fmaxf(acc[m][n][2], acc[m][n][3]));
                int key = (int)((__float_as_uint(qm) & 0xFFFF0000u)
                                | (unsigned)(it*32 + n*4 + qbase));
                ins4(ps[m], key);
            }
    }

    #pragma unroll
    for (int m = 0; m < 4; ++m) {
        int row = rb16b*16 + wm*64 + m*16 + l16;
        size_t base = (size_t)row*NCAND + chunk*CSLOT + wn*16 + lk*4;
        *reinterpret_cast<uint4*>(&cand[base]) =
            make_uint4((unsigned)ps[m][0], (unsigned)ps[m][1],
                       (unsigned)ps[m][2], (unsigned)ps[m][3]);
    }
}

// ---------------------------------------------------------------------------
// Kernel 3a: per row, hierarchical merge 3136 quad candidates -> top-24 quads.
// [unchanged]
// ---------------------------------------------------------------------------
__global__ __launch_bounds__(128, 4)
void merge_topq(const unsigned* __restrict__ cand, int* __restrict__ quads)
{
    __shared__ int Ks[128*8];
    __shared__ int Vs[128*8];
    __shared__ int K24[16*NKF];
    __shared__ int V24[16*NKF];

    const int row  = blockIdx.x;
    const int lane = threadIdx.x;

    int ks[8]; int vs[8];
    #pragma unroll
    for (int i = 0; i < 8; ++i) { ks[i] = 0; vs[i] = 0; }

    const unsigned* rc = cand + (size_t)row*NCAND;
    for (int c = lane; c < NCAND; c += 128) {
        int e  = (int)rc[c];
        int gq = ((c >> 5) << 8) | (e & 255);   // chunk*256 + local quad
        pins<8>(ks, vs, e, gq);
    }
    #pragma unroll
    for (int i = 0; i < 8; ++i) { Ks[lane*8 + i] = ks[i]; Vs[lane*8 + i] = vs[i]; }
    __syncthreads();

    if (lane < 16) {
        int gk[NKF]; int gv[NKF];
        #pragma unroll
        for (int i = 0; i < NKF; ++i) { gk[i] = 0; gv[i] = 0; }
        for (int l = lane*8; l < lane*8 + 8; ++l) {
            for (int i = 0; i < 8; ++i) {          // lane lists sorted desc
                int e = Ks[l*8 + i];
                if (e <= gk[NKF-1]) break;
                pins<NKF>(gk, gv, e, Vs[l*8 + i]);
            }
        }
        #pragma unroll
        for (int i = 0; i < NKF; ++i) { K24[lane*NKF + i] = gk[i]; V24[lane*NKF + i] = gv[i]; }
    }
    __syncthreads();

    if (lane == 0) {
        int gk[NKF]; int gv[NKF];
        #pragma unroll
        for (int i = 0; i < NKF; ++i) { gk[i] = 0; gv[i] = 0; }
        for (int l = 0; l < 16; ++l) {
            for (int i = 0; i < NKF; ++i) {
                int e = K24[l*NKF + i];
                if (e <= gk[NKF-1]) break;
                pins<NKF>(gk, gv, e, V24[l*NKF + i]);
            }
        }
        #pragma unroll
        for (int i = 0; i < NKF; ++i) quads[row*NKF + i] = gv[i];
    }
}

// ---------------------------------------------------------------------------
// Kernel 3b: dense exact rescore. One 16-lane group per dot; 98304 dots.
// [unchanged]
// ---------------------------------------------------------------------------
__global__ __launch_bounds__(256, 8)
void rescore_exact(const int* __restrict__ quads, const int* __restrict__ wordid,
                   const float* __restrict__ weight, double* __restrict__ scores)
{
    const int g = (blockIdx.x * 256 + threadIdx.x) >> 4;   // dot id
    const int l = threadIdx.x & 15;
    const int row = g / NDOT;
    const int ci  = g - row * NDOT;

    const int q   = quads[row*NKF + (ci >> 2)];
    const int col = q*4 + (ci & 3);
    const bool valid = (col < VOCAB);
    const int col_eff = valid ? col : 0;

    const float* qr = weight + (size_t)wordid[row]*KDIM;
    const float* wr = weight + (size_t)col_eff*KDIM;

    double a0 = 0.0, a1 = 0.0;
    #pragma unroll
    for (int k = 0; k < 4; ++k) {
        int sl = (l + 16*k) * 4;
        float4 qa = *reinterpret_cast<const float4*>(qr + sl);
        float4 wb = *reinterpret_cast<const float4*>(wr + sl);
        a0 += (double)qa.x * wb.x + (double)qa.z * wb.z;
        a1 += (double)qa.y * wb.y + (double)qa.w * wb.w;
    }
    if (l < 11) {
        int sl = (l + 64) * 4;
        float4 qa = *reinterpret_cast<const float4*>(qr + sl);
        float4 wb = *reinterpret_cast<const float4*>(wr + sl);
        a0 += (double)qa.x * wb.x + (double)qa.z * wb.z;
        a1 += (double)qa.y * wb.y + (double)qa.w * wb.w;
    }
    double a = a0 + a1;
    #pragma unroll
    for (int m = 1; m < 16; m <<= 1) a += __shfl_xor(a, m);

    if (l == 0) scores[g] = valid ? a : -1e300;
}

// ---------------------------------------------------------------------------
// Kernel 3c: per row, wave-parallel top-11 of the 96 exact scores.
// [unchanged]
// ---------------------------------------------------------------------------
__global__ __launch_bounds__(64, 8)
void final_select(const double* __restrict__ scores, const int* __restrict__ quads,
                  float* __restrict__ out)
{
    const int row  = blockIdx.x;
    const int lane = threadIdx.x;

    double v0 = -INFINITY, v1 = -INFINITY;
    int    c0 = 0x7fffffff, c1 = 0x7fffffff;
    if (lane < NDOT/2) {
        int i0 = lane*2, i1 = lane*2 + 1;
        v0 = scores[(size_t)row*NDOT + i0];
        v1 = scores[(size_t)row*NDOT + i1];
        c0 = quads[row*NKF + (i0 >> 2)]*4 + (i0 & 3);
        c1 = quads[row*NKF + (i1 >> 2)]*4 + (i1 & 3);
    }

    for (int kk = 0; kk < TOPK + 1; ++kk) {
        bool sel = (v0 > v1) || (v0 == v1 && c0 < c1);
        double bv = sel ? v0 : v1;
        int    bc = sel ? c0 : c1;
        #pragma unroll
        for (int m = 1; m < 64; m <<= 1) {
            double ov = __shfl_xor(bv, m);
            int    oc = __shfl_xor(bc, m);
            if (ov > bv || (ov == bv && oc < bc)) { bv = ov; bc = oc; }
        }
        if (kk >= 1 && lane == 0) {
            out[(size_t)row*TOPK + (kk-1)] = (float)bv;
            out[(size_t)BATCH*TOPK + (size_t)row*TOPK + (kk-1)] = (float)bc;
        }
        if (c0 == bc) v0 = -INFINITY;
        if (c1 == bc) v1 = -INFINITY;
    }
}

extern "C" void kernel_launch(void* const* d_in, const int* in_sizes, int n_in,
                              void* d_out, int out_size, void* d_ws, size_t ws_size,
                              hipStream_t stream) {
    const int*   wordid = (const int*)d_in[0];
    const float* weight = (const float*)d_in[1];
    float* out = (float*)d_out;

    const size_t SZ_B = (size_t)NCB_B * NKB * 64 * 16;   // 64,225,280 B
    const size_t SZ_A = (size_t)NCB_A * NKB * 64 * 16;   //    655,360 B

    char* p = (char*)d_ws;
    ushort*   ws_b = (ushort*)p;  p += SZ_B;
    ushort*   ws_a = (ushort*)p;  p += SZ_A;
    unsigned* cand = (unsigned*)p;

    int*    quads  = (int*)ws_a;      // ws_a dead after sim_gemm
    double* scores = (double*)cand;   // cand dead after merge_topq

    convert_frags<<<NCB_B/4 + NCB_A/4, 256, 0, stream>>>(wordid, weight, ws_b, ws_a, NCB_B/4);
    sim_gemm<<<NCHPAD*8, 256, 0, stream>>>(ws_a, ws_b, cand);
    merge_topq<<<BATCH, 128, 0, stream>>>(cand, quads);
    rescore_exact<<<(BATCH*NDOT)/16, 256, 0, stream>>>(quads, wordid, weight, scores);
    final_select<<<BATCH, 64, 0, stream>>>(scores, quads, out);
}

// Round 11
// 243.578 us; speedup vs baseline: 1.1104x; 1.0774x over previous
//
#include <hip/hip_runtime.h>
#include <math.h>

#define BATCH 1024
#define VOCAB 100000
#define KDIM  300
#define TOPK  10

#define NKB    10            // K blocks of 32 (K padded 300 -> 320)
#define NCB_B  6272          // vocab col-blocks of 16, pad vocab to 100352
#define NCB_A  64            // 1024 rows / 16
#define NCC    392           // 256-col chunks (NCB_B/16)
#define NCAND  (NCC*8)       // 3136 candidate u32s per row (8 per chunk)
#define NKF    24            // final quad rescore set -> 96 cols
#define NDOT   (NKF*4)       // 96 exact dots per row

typedef __attribute__((ext_vector_type(8))) short bf16x8;
typedef __attribute__((ext_vector_type(4))) float f32x4;

#define GL2LDS(gsrc, ldst)                                                    \
    __builtin_amdgcn_global_load_lds(                                         \
        (const __attribute__((address_space(1))) void*)(gsrc),                \
        (__attribute__((address_space(3))) void*)(ldst), 16, 0, 0)

__device__ __forceinline__ ushort f2bf(float f) {
    union { float f; unsigned u; } v; v.f = f;
    unsigned r = v.u + 0x7FFFu + ((v.u >> 16) & 1u);  // RNE
    return (ushort)(r >> 16);
}

// depth-4 descending insert, SIGNED keys (sentinel 0)
__device__ __forceinline__ void ins4(int (&l)[4], int e) {
    if (e <= l[3]) return;
    bool g0 = e > l[0], g1 = e > l[1], g2 = e > l[2];
    l[3] = g2 ? l[2] : e;
    l[2] = g2 ? (g1 ? l[1] : e) : l[2];
    l[1] = g1 ? (g0 ? l[0] : e) : l[1];
    l[0] = g0 ? e : l[0];
}

template<int N>
__device__ __forceinline__ void pins(int (&ks)[N], int (&vs)[N], int k, int v) {
    if (k <= ks[N-1]) return;
    #pragma unroll
    for (int p = N-1; p >= 0; --p) {
        bool gt  = k > ks[p];
        bool gtp = (p > 0) ? (k > ks[p-1]) : false;
        int nk = gt ? (gtp ? ks[p-1] : k) : ks[p];
        int nv = gt ? (gtp ? vs[p-1] : v) : vs[p];
        ks[p] = nk; vs[p] = nv;
    }
}

// ---------------------------------------------------------------------------
// Kernel 1: LDS-free fragment packer. [unchanged]
//   B frag (kb, cb):   ws_b[((kb*NCB_B + cb)*64 + lane)*8 .. +7]
//   A frag (kb, rb16): ws_a[((kb*64   + rb16)*64 + lane)*8 .. +7]
// ---------------------------------------------------------------------------
__global__ __launch_bounds__(256)
void convert_frags(const int* __restrict__ wordid, const float* __restrict__ weight,
                   ushort* __restrict__ ws_b, ushort* __restrict__ ws_a, int nb4)
{
    const int t   = threadIdx.x;
    const int w   = t >> 6, l = t & 63;
    const int bid = blockIdx.x;
    const bool is_a = (bid >= nb4);
    const int cb  = (is_a ? (bid - nb4) : bid) * 4 + w;
    ushort* dst = is_a ? ws_a : ws_b;
    const int kstride = is_a ? 64 : NCB_B;

    const int r16  = l & 15;
    const int ksub = (l >> 4) * 8;

    const int row = is_a ? wordid[cb*16 + r16] : (cb*16 + r16);
    const bool vr = (row < VOCAB);
    const float* src = weight + (size_t)(vr ? row : 0) * KDIM;

    #pragma unroll
    for (int kb = 0; kb < NKB; ++kb) {
        const int k0 = kb*32 + ksub;
        float4 a = make_float4(0.f,0.f,0.f,0.f);
        float4 b = make_float4(0.f,0.f,0.f,0.f);
        if (vr) {
            if (k0 + 8 <= KDIM) {
                a = *reinterpret_cast<const float4*>(src + k0);
                b = *reinterpret_cast<const float4*>(src + k0 + 4);
            } else if (k0 + 4 <= KDIM) {
                a = *reinterpret_cast<const float4*>(src + k0);
            }
        }
        uint4 o;
        o.x = (unsigned)f2bf(a.x) | ((unsigned)f2bf(a.y) << 16);
        o.y = (unsigned)f2bf(a.z) | ((unsigned)f2bf(a.w) << 16);
        o.z = (unsigned)f2bf(b.x) | ((unsigned)f2bf(b.y) << 16);
        o.w = (unsigned)f2bf(b.z) | ((unsigned)f2bf(b.w) << 16);
        *reinterpret_cast<uint4*>(&dst[((size_t)kb*kstride + cb)*512 + (size_t)l*8]) = o;
    }
}

// ---------------------------------------------------------------------------
// Kernel 2 (round 11): 8-phase 256x256 template (T3+T4+T5).
// 512 thr / 8 waves (wm 0..1 x wn 0..3); wave tile 128 rows x 64 cols;
// acc[8][4] f32x4. K-tile = 64 (2 kb); 5 K-tiles x 4 phases; per phase:
// {ds_read subtile | stage 4 GL2LDS (phases 0-1) -> barrier ->
//  setprio(1) 16 MFMA setprio(0) -> barrier}; vmcnt(0) once per K-tile.
// LDS: 2 x 64 KB buffers (A 32 KB + B 32 KB each) = 128 KB, 1 block/CU.
// Epilogue: per-lane quad top-2 -> LDS -> 512-thr compress -> 8 cand/chunk.
// Grid 392 col-chunks x 4 row-chunks, bijective XCD swizzle (392%8==0).
// ---------------------------------------------------------------------------
__global__ __launch_bounds__(512, 2)
void sim_gemm(const ushort* __restrict__ ws_a, const ushort* __restrict__ ws_b,
              unsigned* __restrict__ cand)
{
    __shared__ __align__(16) char pool[131072];

    const int id = blockIdx.x;
    const int cc = (id & 7) + ((id >> 5) << 3);   // col-chunk 0..391
    const int rc = (id >> 3) & 3;                 // row-chunk 0..3

    const int t    = threadIdx.x;
    const int wid  = t >> 6, lane = t & 63;
    const int wm   = wid >> 2, wn = wid & 3;
    const int l16  = lane & 15, lk = lane >> 4;

    // stage one 1 KB frag slot of K-tile kt into buffer buf.
    // slots: 0..31 = A [kb][rb16], 32..63 = B [kb][cb]. wave w owns w*8..w*8+7.
    auto stage_slot = [&](int kt, int slot, int buf) {
        char* ldst = pool + buf*65536 + slot*1024;
        const ushort* src;
        if (slot < 32) {
            src = ws_a + (((size_t)(kt*2 + (slot>>4))*64) + rc*16 + (slot & 15))*512
                       + (size_t)lane*8;
        } else {
            int s2 = slot - 32;
            src = ws_b + (((size_t)(kt*2 + (s2>>4))*NCB_B) + cc*16 + (s2 & 15))*512
                       + (size_t)lane*8;
        }
        GL2LDS(src, (ushort*)ldst);
    };

    f32x4 acc[8][4] = {};

    // prologue: stage K-tile 0 into buffer 0, drain, barrier
    #pragma unroll
    for (int j = 0; j < 8; ++j) stage_slot(0, wid*8 + j, 0);
    asm volatile("s_waitcnt vmcnt(0)" ::: "memory");
    __builtin_amdgcn_s_barrier();
    asm volatile("" ::: "memory");

    for (int kt = 0; kt < 5; ++kt) {
        const int buf = kt & 1;
        const ushort* Ab = (const ushort*)(pool + buf*65536);
        const ushort* Bb = (const ushort*)(pool + buf*65536 + 32768);

        bf16x8 bfr[2][4];

        #pragma unroll
        for (int p = 0; p < 4; ++p) {
            // --- ds-load register subtile ---
            if (p == 0) {
                #pragma unroll
                for (int kb = 0; kb < 2; ++kb)
                    #pragma unroll
                    for (int nf = 0; nf < 4; ++nf)
                        bfr[kb][nf] = *reinterpret_cast<const bf16x8*>(
                            Bb + (size_t)(kb*16 + wn*4 + nf)*512 + lane*8);
            }
            bf16x8 af[2][2];
            #pragma unroll
            for (int kb = 0; kb < 2; ++kb)
                #pragma unroll
                for (int m2 = 0; m2 < 2; ++m2)
                    af[kb][m2] = *reinterpret_cast<const bf16x8*>(
                        Ab + (size_t)(kb*16 + wm*8 + p*2 + m2)*512 + lane*8);

            // --- stage next K-tile (phases 0-1: 4 issues each) ---
            if (p < 2 && kt < 4) {
                #pragma unroll
                for (int jj = 0; jj < 4; ++jj)
                    stage_slot(kt + 1, wid*8 + p*4 + jj, buf ^ 1);
            }

            __builtin_amdgcn_s_barrier();
            asm volatile("" ::: "memory");

            // --- MFMA cluster (quadrant p: rows mf = p*2, p*2+1) ---
            __builtin_amdgcn_s_setprio(1);
            #pragma unroll
            for (int m2 = 0; m2 < 2; ++m2)
                #pragma unroll
                for (int nf = 0; nf < 4; ++nf) {
                    acc[p*2+m2][nf] = __builtin_amdgcn_mfma_f32_16x16x32_bf16(
                        bfr[0][nf], af[0][m2], acc[p*2+m2][nf], 0, 0, 0);
                    acc[p*2+m2][nf] = __builtin_amdgcn_mfma_f32_16x16x32_bf16(
                        bfr[1][nf], af[1][m2], acc[p*2+m2][nf], 0, 0, 0);
                }
            __builtin_amdgcn_s_setprio(0);

            // K-tile boundary: ensure next buffer landed (counted once/K-tile)
            if (p == 3 && kt < 4) {
                asm volatile("s_waitcnt vmcnt(0)" ::: "memory");
            }
            __builtin_amdgcn_s_barrier();
            asm volatile("" ::: "memory");
        }
    }

    // --- epilogue: quad scan -> per-lane top2 -> LDS (stride-33 pad) ---
    int* Cls = (int*)pool;   // 256*33*4 = 33.8 KB, reuses buffer 0 region
    #pragma unroll
    for (int mf = 0; mf < 8; ++mf) {
        int k0 = 0, k1 = 0;
        #pragma unroll
        for (int nf = 0; nf < 4; ++nf) {
            float qm = fmaxf(fmaxf(acc[mf][nf][0], acc[mf][nf][1]),
                             fmaxf(acc[mf][nf][2], acc[mf][nf][3]));
            int key = (int)((__float_as_uint(qm) & 0xFFFF0000u)
                            | (unsigned)(wn*16 + nf*4 + lk));   // quad-in-chunk, 6 bits
            if (key > k0)      { k1 = k0; k0 = key; }
            else if (key > k1) { k1 = key; }
        }
        int row = wm*128 + mf*16 + l16;
        int ent = wn*4 + lk;
        Cls[row*33 + ent*2 + 0] = k0;
        Cls[row*33 + ent*2 + 1] = k1;
    }
    __syncthreads();

    // --- compress: thread -> (row, half of 16 entries) -> depth-4 -> cand ---
    {
        int row  = t >> 1, half = t & 1;
        int ks[4] = {0, 0, 0, 0};
        #pragma unroll
        for (int j = 0; j < 16; ++j)
            ins4(ks, Cls[row*33 + half*16 + j]);
        int grow = rc*256 + row;
        size_t base = (size_t)grow*NCAND + cc*8 + half*4;
        *reinterpret_cast<uint4*>(&cand[base]) =
            make_uint4((unsigned)ks[0], (unsigned)ks[1],
                       (unsigned)ks[2], (unsigned)ks[3]);
    }
}

// ---------------------------------------------------------------------------
// Kernel 3a: per row, hierarchical merge 3136 quad candidates -> top-24 quads.
// (decode updated: 8 slots/chunk, 6-bit quad payload)
// ---------------------------------------------------------------------------
__global__ __launch_bounds__(128, 4)
void merge_topq(const unsigned* __restrict__ cand, int* __restrict__ quads)
{
    __shared__ int Ks[128*8];
    __shared__ int Vs[128*8];
    __shared__ int K24[16*NKF];
    __shared__ int V24[16*NKF];

    const int row  = blockIdx.x;
    const int lane = threadIdx.x;

    int ks[8]; int vs[8];
    #pragma unroll
    for (int i = 0; i < 8; ++i) { ks[i] = 0; vs[i] = 0; }

    const unsigned* rc = cand + (size_t)row*NCAND;
    for (int c = lane; c < NCAND; c += 128) {
        int e  = (int)rc[c];
        int gq = ((c >> 3) << 6) | (e & 63);   // chunk*64 + quad-in-chunk
        pins<8>(ks, vs, e, gq);
    }
    #pragma unroll
    for (int i = 0; i < 8; ++i) { Ks[lane*8 + i] = ks[i]; Vs[lane*8 + i] = vs[i]; }
    __syncthreads();

    if (lane < 16) {
        int gk[NKF]; int gv[NKF];
        #pragma unroll
        for (int i = 0; i < NKF; ++i) { gk[i] = 0; gv[i] = 0; }
        for (int l = lane*8; l < lane*8 + 8; ++l) {
            for (int i = 0; i < 8; ++i) {
                int e = Ks[l*8 + i];
                if (e <= gk[NKF-1]) break;
                pins<NKF>(gk, gv, e, Vs[l*8 + i]);
            }
        }
        #pragma unroll
        for (int i = 0; i < NKF; ++i) { K24[lane*NKF + i] = gk[i]; V24[lane*NKF + i] = gv[i]; }
    }
    __syncthreads();

    if (lane == 0) {
        int gk[NKF]; int gv[NKF];
        #pragma unroll
        for (int i = 0; i < NKF; ++i) { gk[i] = 0; gv[i] = 0; }
        for (int l = 0; l < 16; ++l) {
            for (int i = 0; i < NKF; ++i) {
                int e = K24[l*NKF + i];
                if (e <= gk[NKF-1]) break;
                pins<NKF>(gk, gv, e, V24[l*NKF + i]);
            }
        }
        #pragma unroll
        for (int i = 0; i < NKF; ++i) quads[row*NKF + i] = gv[i];
    }
}

// ---------------------------------------------------------------------------
// Kernel 3b: dense exact rescore. One 16-lane group per dot. [unchanged]
// ---------------------------------------------------------------------------
__global__ __launch_bounds__(256, 8)
void rescore_exact(const int* __restrict__ quads, const int* __restrict__ wordid,
                   const float* __restrict__ weight, double* __restrict__ scores)
{
    const int g = (blockIdx.x * 256 + threadIdx.x) >> 4;
    const int l = threadIdx.x & 15;
    const int row = g / NDOT;
    const int ci  = g - row * NDOT;

    const int q   = quads[row*NKF + (ci >> 2)];
    const int col = q*4 + (ci & 3);
    const bool valid = (col < VOCAB);
    const int col_eff = valid ? col : 0;

    const float* qr = weight + (size_t)wordid[row]*KDIM;
    const float* wr = weight + (size_t)col_eff*KDIM;

    double a0 = 0.0, a1 = 0.0;
    #pragma unroll
    for (int k = 0; k < 4; ++k) {
        int sl = (l + 16*k) * 4;
        float4 qa = *reinterpret_cast<const float4*>(qr + sl);
        float4 wb = *reinterpret_cast<const float4*>(wr + sl);
        a0 += (double)qa.x * wb.x + (double)qa.z * wb.z;
        a1 += (double)qa.y * wb.y + (double)qa.w * wb.w;
    }
    if (l < 11) {
        int sl = (l + 64) * 4;
        float4 qa = *reinterpret_cast<const float4*>(qr + sl);
        float4 wb = *reinterpret_cast<const float4*>(wr + sl);
        a0 += (double)qa.x * wb.x + (double)qa.z * wb.z;
        a1 += (double)qa.y * wb.y + (double)qa.w * wb.w;
    }
    double a = a0 + a1;
    #pragma unroll
    for (int m = 1; m < 16; m <<= 1) a += __shfl_xor(a, m);

    if (l == 0) scores[g] = valid ? a : -1e300;
}

// ---------------------------------------------------------------------------
// Kernel 3c: per row, wave-parallel top-11 of the 96 exact scores. [unchanged]
// ---------------------------------------------------------------------------
__global__ __launch_bounds__(64, 8)
void final_select(const double* __restrict__ scores, const int* __restrict__ quads,
                  float* __restrict__ out)
{
    const int row  = blockIdx.x;
    const int lane = threadIdx.x;

    double v0 = -INFINITY, v1 = -INFINITY;
    int    c0 = 0x7fffffff, c1 = 0x7fffffff;
    if (lane < NDOT/2) {
        int i0 = lane*2, i1 = lane*2 + 1;
        v0 = scores[(size_t)row*NDOT + i0];
        v1 = scores[(size_t)row*NDOT + i1];
        c0 = quads[row*NKF + (i0 >> 2)]*4 + (i0 & 3);
        c1 = quads[row*NKF + (i1 >> 2)]*4 + (i1 & 3);
    }

    for (int kk = 0; kk < TOPK + 1; ++kk) {
        bool sel = (v0 > v1) || (v0 == v1 && c0 < c1);
        double bv = sel ? v0 : v1;
        int    bc = sel ? c0 : c1;
        #pragma unroll
        for (int m = 1; m < 64; m <<= 1) {
            double ov = __shfl_xor(bv, m);
            int    oc = __shfl_xor(bc, m);
            if (ov > bv || (ov == bv && oc < bc)) { bv = ov; bc = oc; }
        }
        if (kk >= 1 && lane == 0) {
            out[(size_t)row*TOPK + (kk-1)] = (float)bv;
            out[(size_t)BATCH*TOPK + (size_t)row*TOPK + (kk-1)] = (float)bc;
        }
        if (c0 == bc) v0 = -INFINITY;
        if (c1 == bc) v1 = -INFINITY;
    }
}

extern "C" void kernel_launch(void* const* d_in, const int* in_sizes, int n_in,
                              void* d_out, int out_size, void* d_ws, size_t ws_size,
                              hipStream_t stream) {
    const int*   wordid = (const int*)d_in[0];
    const float* weight = (const float*)d_in[1];
    float* out = (float*)d_out;

    const size_t SZ_B = (size_t)NCB_B * NKB * 64 * 16;   // 64,225,280 B
    const size_t SZ_A = (size_t)NCB_A * NKB * 64 * 16;   //    655,360 B

    char* p = (char*)d_ws;
    ushort*   ws_b = (ushort*)p;  p += SZ_B;
    ushort*   ws_a = (ushort*)p;  p += SZ_A;
    unsigned* cand = (unsigned*)p;

    int*    quads  = (int*)ws_a;      // ws_a dead after sim_gemm
    double* scores = (double*)cand;   // cand dead after merge_topq

    convert_frags<<<NCB_B/4 + NCB_A/4, 256, 0, stream>>>(wordid, weight, ws_b, ws_a, NCB_B/4);
    sim_gemm<<<NCC*4, 512, 0, stream>>>(ws_a, ws_b, cand);
    merge_topq<<<BATCH, 128, 0, stream>>>(cand, quads);
    rescore_exact<<<(BATCH*NDOT)/16, 256, 0, stream>>>(quads, wordid, weight, scores);
    final_select<<<BATCH, 64, 0, stream>>>(scores, quads, out);
}

// Round 12
// 185.478 us; speedup vs baseline: 1.4583x; 1.3132x over previous
//
#include <hip/hip_runtime.h>
#include <math.h>

#define BATCH 1024
#define VOCAB 100000
#define KDIM  300
#define TOPK  10

#define NKB    10            // K blocks of 32 (K padded 300 -> 320)
#define NCB_B  6272          // vocab col-blocks of 16, pad vocab to 100352
#define NCB_A  64            // 1024 rows / 16
#define NCC    392           // 256-col chunks (NCB_B/16)
#define NCAND  (NCC*8)       // 3136 candidate u32s per row (8 per chunk)
#define NKF    24            // final quad rescore set -> 96 cols
#define NDOT   (NKF*4)       // 96 exact dots per row

typedef __attribute__((ext_vector_type(8))) short bf16x8;
typedef __attribute__((ext_vector_type(4))) float f32x4;
typedef unsigned long long u64;

#define GL2LDS(gsrc, ldst)                                                    \
    __builtin_amdgcn_global_load_lds(                                         \
        (const __attribute__((address_space(1))) void*)(gsrc),                \
        (__attribute__((address_space(3))) void*)(ldst), 16, 0, 0)

__device__ __forceinline__ ushort f2bf(float f) {
    union { float f; unsigned u; } v; v.f = f;
    unsigned r = v.u + 0x7FFFu + ((v.u >> 16) & 1u);  // RNE
    return (ushort)(r >> 16);
}

// depth-4 descending insert, SIGNED keys (sentinel 0)
__device__ __forceinline__ void ins4(int (&l)[4], int e) {
    if (e <= l[3]) return;
    bool g0 = e > l[0], g1 = e > l[1], g2 = e > l[2];
    l[3] = g2 ? l[2] : e;
    l[2] = g2 ? (g1 ? l[1] : e) : l[2];
    l[1] = g1 ? (g0 ? l[0] : e) : l[1];
    l[0] = g0 ? e : l[0];
}

// descending u64 insert, depth N, fully unrolled (sentinel 0)
template<int N>
__device__ __forceinline__ void pins64(u64 (&ks)[N], u64 k) {
    if (k <= ks[N-1]) return;
    #pragma unroll
    for (int p = N-1; p >= 0; --p) {
        bool gt  = k > ks[p];
        bool gtp = (p > 0) ? (k > ks[p-1]) : false;
        ks[p] = gt ? (gtp ? ks[p-1] : k) : ks[p];
    }
}

// ---------------------------------------------------------------------------
// Kernel 1: LDS-free fragment packer. [unchanged]
//   B frag (kb, cb):   ws_b[((kb*NCB_B + cb)*64 + lane)*8 .. +7]
//   A frag (kb, rb16): ws_a[((kb*64   + rb16)*64 + lane)*8 .. +7]
// ---------------------------------------------------------------------------
__global__ __launch_bounds__(256)
void convert_frags(const int* __restrict__ wordid, const float* __restrict__ weight,
                   ushort* __restrict__ ws_b, ushort* __restrict__ ws_a, int nb4)
{
    const int t   = threadIdx.x;
    const int w   = t >> 6, l = t & 63;
    const int bid = blockIdx.x;
    const bool is_a = (bid >= nb4);
    const int cb  = (is_a ? (bid - nb4) : bid) * 4 + w;
    ushort* dst = is_a ? ws_a : ws_b;
    const int kstride = is_a ? 64 : NCB_B;

    const int r16  = l & 15;
    const int ksub = (l >> 4) * 8;

    const int row = is_a ? wordid[cb*16 + r16] : (cb*16 + r16);
    const bool vr = (row < VOCAB);
    const float* src = weight + (size_t)(vr ? row : 0) * KDIM;

    #pragma unroll
    for (int kb = 0; kb < NKB; ++kb) {
        const int k0 = kb*32 + ksub;
        float4 a = make_float4(0.f,0.f,0.f,0.f);
        float4 b = make_float4(0.f,0.f,0.f,0.f);
        if (vr) {
            if (k0 + 8 <= KDIM) {
                a = *reinterpret_cast<const float4*>(src + k0);
                b = *reinterpret_cast<const float4*>(src + k0 + 4);
            } else if (k0 + 4 <= KDIM) {
                a = *reinterpret_cast<const float4*>(src + k0);
            }
        }
        uint4 o;
        o.x = (unsigned)f2bf(a.x) | ((unsigned)f2bf(a.y) << 16);
        o.y = (unsigned)f2bf(a.z) | ((unsigned)f2bf(a.w) << 16);
        o.z = (unsigned)f2bf(b.x) | ((unsigned)f2bf(b.y) << 16);
        o.w = (unsigned)f2bf(b.z) | ((unsigned)f2bf(b.w) << 16);
        *reinterpret_cast<uint4*>(&dst[((size_t)kb*kstride + cb)*512 + (size_t)l*8]) = o;
    }
}

// ---------------------------------------------------------------------------
// Kernel 2: 8-phase 256x256 template (T3+T4+T5). [unchanged from round 11]
// ---------------------------------------------------------------------------
__global__ __launch_bounds__(512, 2)
void sim_gemm(const ushort* __restrict__ ws_a, const ushort* __restrict__ ws_b,
              unsigned* __restrict__ cand)
{
    __shared__ __align__(16) char pool[131072];

    const int id = blockIdx.x;
    const int cc = (id & 7) + ((id >> 5) << 3);   // col-chunk 0..391
    const int rc = (id >> 3) & 3;                 // row-chunk 0..3

    const int t    = threadIdx.x;
    const int wid  = t >> 6, lane = t & 63;
    const int wm   = wid >> 2, wn = wid & 3;
    const int l16  = lane & 15, lk = lane >> 4;

    auto stage_slot = [&](int kt, int slot, int buf) {
        char* ldst = pool + buf*65536 + slot*1024;
        const ushort* src;
        if (slot < 32) {
            src = ws_a + (((size_t)(kt*2 + (slot>>4))*64) + rc*16 + (slot & 15))*512
                       + (size_t)lane*8;
        } else {
            int s2 = slot - 32;
            src = ws_b + (((size_t)(kt*2 + (s2>>4))*NCB_B) + cc*16 + (s2 & 15))*512
                       + (size_t)lane*8;
        }
        GL2LDS(src, (ushort*)ldst);
    };

    f32x4 acc[8][4] = {};

    #pragma unroll
    for (int j = 0; j < 8; ++j) stage_slot(0, wid*8 + j, 0);
    asm volatile("s_waitcnt vmcnt(0)" ::: "memory");
    __builtin_amdgcn_s_barrier();
    asm volatile("" ::: "memory");

    for (int kt = 0; kt < 5; ++kt) {
        const int buf = kt & 1;
        const ushort* Ab = (const ushort*)(pool + buf*65536);
        const ushort* Bb = (const ushort*)(pool + buf*65536 + 32768);

        bf16x8 bfr[2][4];

        #pragma unroll
        for (int p = 0; p < 4; ++p) {
            if (p == 0) {
                #pragma unroll
                for (int kb = 0; kb < 2; ++kb)
                    #pragma unroll
                    for (int nf = 0; nf < 4; ++nf)
                        bfr[kb][nf] = *reinterpret_cast<const bf16x8*>(
                            Bb + (size_t)(kb*16 + wn*4 + nf)*512 + lane*8);
            }
            bf16x8 af[2][2];
            #pragma unroll
            for (int kb = 0; kb < 2; ++kb)
                #pragma unroll
                for (int m2 = 0; m2 < 2; ++m2)
                    af[kb][m2] = *reinterpret_cast<const bf16x8*>(
                        Ab + (size_t)(kb*16 + wm*8 + p*2 + m2)*512 + lane*8);

            if (p < 2 && kt < 4) {
                #pragma unroll
                for (int jj = 0; jj < 4; ++jj)
                    stage_slot(kt + 1, wid*8 + p*4 + jj, buf ^ 1);
            }

            __builtin_amdgcn_s_barrier();
            asm volatile("" ::: "memory");

            __builtin_amdgcn_s_setprio(1);
            #pragma unroll
            for (int m2 = 0; m2 < 2; ++m2)
                #pragma unroll
                for (int nf = 0; nf < 4; ++nf) {
                    acc[p*2+m2][nf] = __builtin_amdgcn_mfma_f32_16x16x32_bf16(
                        bfr[0][nf], af[0][m2], acc[p*2+m2][nf], 0, 0, 0);
                    acc[p*2+m2][nf] = __builtin_amdgcn_mfma_f32_16x16x32_bf16(
                        bfr[1][nf], af[1][m2], acc[p*2+m2][nf], 0, 0, 0);
                }
            __builtin_amdgcn_s_setprio(0);

            if (p == 3 && kt < 4) {
                asm volatile("s_waitcnt vmcnt(0)" ::: "memory");
            }
            __builtin_amdgcn_s_barrier();
            asm volatile("" ::: "memory");
        }
    }

    int* Cls = (int*)pool;
    #pragma unroll
    for (int mf = 0; mf < 8; ++mf) {
        int k0 = 0, k1 = 0;
        #pragma unroll
        for (int nf = 0; nf < 4; ++nf) {
            float qm = fmaxf(fmaxf(acc[mf][nf][0], acc[mf][nf][1]),
                             fmaxf(acc[mf][nf][2], acc[mf][nf][3]));
            int key = (int)((__float_as_uint(qm) & 0xFFFF0000u)
                            | (unsigned)(wn*16 + nf*4 + lk));
            if (key > k0)      { k1 = k0; k0 = key; }
            else if (key > k1) { k1 = key; }
        }
        int row = wm*128 + mf*16 + l16;
        int ent = wn*4 + lk;
        Cls[row*33 + ent*2 + 0] = k0;
        Cls[row*33 + ent*2 + 1] = k1;
    }
    __syncthreads();

    {
        int row  = t >> 1, half = t & 1;
        int ks[4] = {0, 0, 0, 0};
        #pragma unroll
        for (int j = 0; j < 16; ++j)
            ins4(ks, Cls[row*33 + half*16 + j]);
        int grow = rc*256 + row;
        size_t base = (size_t)grow*NCAND + cc*8 + half*4;
        *reinterpret_cast<uint4*>(&cand[base]) =
            make_uint4((unsigned)ks[0], (unsigned)ks[1],
                       (unsigned)ks[2], (unsigned)ks[3]);
    }
}

// ---------------------------------------------------------------------------
// Kernel 3a (round 12 rewrite): wave-parallel exact top-24 per row.
// 4 waves/row; wave w holds candidates c = w*784 + i*64 + lane (i<13) as
// packed u64 (sign-flipped key << 32 | global quad id) in an EXACT sorted
// depth-13 register list. 24 rounds of 64-lane shfl_xor argmax + pop give
// the wave's exact top-24 (sorted). Stage 2: wave 0 merges the 4 sorted
// 24-lists (2 items/lane) with the same extraction. All lanes busy; no
// serial lane-0 merge. Quad ids are unique per row -> deterministic.
// ---------------------------------------------------------------------------
__global__ __launch_bounds__(256, 8)
void merge_topq(const unsigned* __restrict__ cand, int* __restrict__ quads)
{
    __shared__ u64 Wv[4*NKF];

    const int row  = blockIdx.x;
    const int t    = threadIdx.x;
    const int wid  = t >> 6, lane = t & 63;

    // gather: exact sorted depth-13 per lane
    u64 a[13];
    #pragma unroll
    for (int i = 0; i < 13; ++i) a[i] = 0ull;

    const unsigned* rc = cand + (size_t)row*NCAND;
    #pragma unroll
    for (int i = 0; i < 13; ++i) {
        int off = i*64 + lane;
        if (off < 784) {
            int c = wid*784 + off;
            unsigned e = rc[c];
            u64 comb = ((u64)(e ^ 0x80000000u) << 32)
                     | (unsigned)(((c >> 3) << 6) | (e & 63u));
            pins64<13>(a, comb);
        }
    }

    // wave-parallel extraction of top-24
    u64 mywin = 0ull;
    for (int k = 0; k < NKF; ++k) {
        u64 h = a[0], r = h;
        #pragma unroll
        for (int m = 1; m < 64; m <<= 1) {
            u64 o = __shfl_xor(r, m);
            r = (o > r) ? o : r;
        }
        bool win = (h == r);
        #pragma unroll
        for (int j = 0; j < 12; ++j) a[j] = win ? a[j+1] : a[j];
        a[12] = win ? 0ull : a[12];
        mywin = (lane == k) ? r : mywin;
    }
    if (lane < NKF) Wv[wid*NKF + lane] = mywin;
    __syncthreads();

    // stage 2: wave 0 merges 96 entries (2 per lane) -> top-24
    if (wid == 0) {
        u64 b0 = Wv[lane];
        u64 b1 = (lane < 32) ? Wv[lane + 64] : 0ull;
        if (b1 > b0) { u64 tmp = b0; b0 = b1; b1 = tmp; }

        u64 fin = 0ull;
        for (int k = 0; k < NKF; ++k) {
            u64 h = b0, r = h;
            #pragma unroll
            for (int m = 1; m < 64; m <<= 1) {
                u64 o = __shfl_xor(r, m);
                r = (o > r) ? o : r;
            }
            bool win = (h == r);
            b0 = win ? b1 : b0;
            b1 = win ? 0ull : b1;
            fin = (lane == k) ? r : fin;
        }
        if (lane < NKF) quads[row*NKF + lane] = (int)(fin & 0xffffffffull);
    }
}

// ---------------------------------------------------------------------------
// Kernel 3b: dense exact rescore. One 16-lane group per dot. [unchanged]
// ---------------------------------------------------------------------------
__global__ __launch_bounds__(256, 8)
void rescore_exact(const int* __restrict__ quads, const int* __restrict__ wordid,
                   const float* __restrict__ weight, double* __restrict__ scores)
{
    const int g = (blockIdx.x * 256 + threadIdx.x) >> 4;
    const int l = threadIdx.x & 15;
    const int row = g / NDOT;
    const int ci  = g - row * NDOT;

    const int q   = quads[row*NKF + (ci >> 2)];
    const int col = q*4 + (ci & 3);
    const bool valid = (col < VOCAB);
    const int col_eff = valid ? col : 0;

    const float* qr = weight + (size_t)wordid[row]*KDIM;
    const float* wr = weight + (size_t)col_eff*KDIM;

    double a0 = 0.0, a1 = 0.0;
    #pragma unroll
    for (int k = 0; k < 4; ++k) {
        int sl = (l + 16*k) * 4;
        float4 qa = *reinterpret_cast<const float4*>(qr + sl);
        float4 wb = *reinterpret_cast<const float4*>(wr + sl);
        a0 += (double)qa.x * wb.x + (double)qa.z * wb.z;
        a1 += (double)qa.y * wb.y + (double)qa.w * wb.w;
    }
    if (l < 11) {
        int sl = (l + 64) * 4;
        float4 qa = *reinterpret_cast<const float4*>(qr + sl);
        float4 wb = *reinterpret_cast<const float4*>(wr + sl);
        a0 += (double)qa.x * wb.x + (double)qa.z * wb.z;
        a1 += (double)qa.y * wb.y + (double)qa.w * wb.w;
    }
    double a = a0 + a1;
    #pragma unroll
    for (int m = 1; m < 16; m <<= 1) a += __shfl_xor(a, m);

    if (l == 0) scores[g] = valid ? a : -1e300;
}

// ---------------------------------------------------------------------------
// Kernel 3c: per row, wave-parallel top-11 of the 96 exact scores. [unchanged]
// ---------------------------------------------------------------------------
__global__ __launch_bounds__(64, 8)
void final_select(const double* __restrict__ scores, const int* __restrict__ quads,
                  float* __restrict__ out)
{
    const int row  = blockIdx.x;
    const int lane = threadIdx.x;

    double v0 = -INFINITY, v1 = -INFINITY;
    int    c0 = 0x7fffffff, c1 = 0x7fffffff;
    if (lane < NDOT/2) {
        int i0 = lane*2, i1 = lane*2 + 1;
        v0 = scores[(size_t)row*NDOT + i0];
        v1 = scores[(size_t)row*NDOT + i1];
        c0 = quads[row*NKF + (i0 >> 2)]*4 + (i0 & 3);
        c1 = quads[row*NKF + (i1 >> 2)]*4 + (i1 & 3);
    }

    for (int kk = 0; kk < TOPK + 1; ++kk) {
        bool sel = (v0 > v1) || (v0 == v1 && c0 < c1);
        double bv = sel ? v0 : v1;
        int    bc = sel ? c0 : c1;
        #pragma unroll
        for (int m = 1; m < 64; m <<= 1) {
            double ov = __shfl_xor(bv, m);
            int    oc = __shfl_xor(bc, m);
            if (ov > bv || (ov == bv && oc < bc)) { bv = ov; bc = oc; }
        }
        if (kk >= 1 && lane == 0) {
            out[(size_t)row*TOPK + (kk-1)] = (float)bv;
            out[(size_t)BATCH*TOPK + (size_t)row*TOPK + (kk-1)] = (float)bc;
        }
        if (c0 == bc) v0 = -INFINITY;
        if (c1 == bc) v1 = -INFINITY;
    }
}

extern "C" void kernel_launch(void* const* d_in, const int* in_sizes, int n_in,
                              void* d_out, int out_size, void* d_ws, size_t ws_size,
                              hipStream_t stream) {
    const int*   wordid = (const int*)d_in[0];
    const float* weight = (const float*)d_in[1];
    float* out = (float*)d_out;

    const size_t SZ_B = (size_t)NCB_B * NKB * 64 * 16;   // 64,225,280 B
    const size_t SZ_A = (size_t)NCB_A * NKB * 64 * 16;   //    655,360 B

    char* p = (char*)d_ws;
    ushort*   ws_b = (ushort*)p;  p += SZ_B;
    ushort*   ws_a = (ushort*)p;  p += SZ_A;
    unsigned* cand = (unsigned*)p;

    int*    quads  = (int*)ws_a;      // ws_a dead after sim_gemm
    double* scores = (double*)cand;   // cand dead after merge_topq

    convert_frags<<<NCB_B/4 + NCB_A/4, 256, 0, stream>>>(wordid, weight, ws_b, ws_a, NCB_B/4);
    sim_gemm<<<NCC*4, 512, 0, stream>>>(ws_a, ws_b, cand);
    merge_topq<<<BATCH, 256, 0, stream>>>(cand, quads);
    rescore_exact<<<(BATCH*NDOT)/16, 256, 0, stream>>>(quads, wordid, weight, scores);
    final_select<<<BATCH, 64, 0, stream>>>(scores, quads, out);
}

// Round 13
// 182.693 us; speedup vs baseline: 1.4805x; 1.0152x over previous
//
#include <hip/hip_runtime.h>
#include <math.h>

#define BATCH 1024
#define VOCAB 100000
#define KDIM  300
#define TOPK  10

#define NKB    10            // K blocks of 32 (K padded 300 -> 320)
#define NCB_B  6272          // vocab col-blocks of 16, pad vocab to 100352
#define NCB_A  64            // 1024 rows / 16
#define NCC    392           // 256-col chunks (NCB_B/16)
#define NCAND  (NCC*8)       // 3136 candidate u32s per row (8 per chunk)
#define NKF    24            // final quad rescore set -> 96 cols
#define NDOT   (NKF*4)       // 96 exact dots per row

typedef __attribute__((ext_vector_type(8))) short bf16x8;
typedef __attribute__((ext_vector_type(4))) float f32x4;
typedef unsigned long long u64;

#define GL2LDS(gsrc, ldst)                                                    \
    __builtin_amdgcn_global_load_lds(                                         \
        (const __attribute__((address_space(1))) void*)(gsrc),                \
        (__attribute__((address_space(3))) void*)(ldst), 16, 0, 0)

__device__ __forceinline__ ushort f2bf(float f) {
    union { float f; unsigned u; } v; v.f = f;
    unsigned r = v.u + 0x7FFFu + ((v.u >> 16) & 1u);  // RNE
    return (ushort)(r >> 16);
}

// depth-4 descending insert, SIGNED keys (sentinel 0)
__device__ __forceinline__ void ins4(int (&l)[4], int e) {
    if (e <= l[3]) return;
    bool g0 = e > l[0], g1 = e > l[1], g2 = e > l[2];
    l[3] = g2 ? l[2] : e;
    l[2] = g2 ? (g1 ? l[1] : e) : l[2];
    l[1] = g1 ? (g0 ? l[0] : e) : l[1];
    l[0] = g0 ? e : l[0];
}

// descending u64 insert, depth N, fully unrolled (sentinel 0)
template<int N>
__device__ __forceinline__ void pins64(u64 (&ks)[N], u64 k) {
    if (k <= ks[N-1]) return;
    #pragma unroll
    for (int p = N-1; p >= 0; --p) {
        bool gt  = k > ks[p];
        bool gtp = (p > 0) ? (k > ks[p-1]) : false;
        ks[p] = gt ? (gtp ? ks[p-1] : k) : ks[p];
    }
}

// ---------------------------------------------------------------------------
// Kernel 1: LDS-free fragment packer. [unchanged]
//   B frag (kb, cb):   ws_b[((kb*NCB_B + cb)*64 + lane)*8 .. +7]
//   A frag (kb, rb16): ws_a[((kb*64   + rb16)*64 + lane)*8 .. +7]
// ---------------------------------------------------------------------------
__global__ __launch_bounds__(256)
void convert_frags(const int* __restrict__ wordid, const float* __restrict__ weight,
                   ushort* __restrict__ ws_b, ushort* __restrict__ ws_a, int nb4)
{
    const int t   = threadIdx.x;
    const int w   = t >> 6, l = t & 63;
    const int bid = blockIdx.x;
    const bool is_a = (bid >= nb4);
    const int cb  = (is_a ? (bid - nb4) : bid) * 4 + w;
    ushort* dst = is_a ? ws_a : ws_b;
    const int kstride = is_a ? 64 : NCB_B;

    const int r16  = l & 15;
    const int ksub = (l >> 4) * 8;

    const int row = is_a ? wordid[cb*16 + r16] : (cb*16 + r16);
    const bool vr = (row < VOCAB);
    const float* src = weight + (size_t)(vr ? row : 0) * KDIM;

    #pragma unroll
    for (int kb = 0; kb < NKB; ++kb) {
        const int k0 = kb*32 + ksub;
        float4 a = make_float4(0.f,0.f,0.f,0.f);
        float4 b = make_float4(0.f,0.f,0.f,0.f);
        if (vr) {
            if (k0 + 8 <= KDIM) {
                a = *reinterpret_cast<const float4*>(src + k0);
                b = *reinterpret_cast<const float4*>(src + k0 + 4);
            } else if (k0 + 4 <= KDIM) {
                a = *reinterpret_cast<const float4*>(src + k0);
            }
        }
        uint4 o;
        o.x = (unsigned)f2bf(a.x) | ((unsigned)f2bf(a.y) << 16);
        o.y = (unsigned)f2bf(a.z) | ((unsigned)f2bf(a.w) << 16);
        o.z = (unsigned)f2bf(b.x) | ((unsigned)f2bf(b.y) << 16);
        o.w = (unsigned)f2bf(b.z) | ((unsigned)f2bf(b.w) << 16);
        *reinterpret_cast<uint4*>(&dst[((size_t)kb*kstride + cb)*512 + (size_t)l*8]) = o;
    }
}

// ---------------------------------------------------------------------------
// Kernel 2 (round 13): 256x256 tile, de-barriered K-loop.
// K=320 gives only a 5-iteration K-loop: m201's per-phase barrier pacing
// (40 barriers/block) is overhead here, not discipline. Correctness needs
// exactly ONE {per-wave vmcnt(0); s_barrier} per K-tile boundary. All 8
// stage-slots are issued at K-tile entry (full K-tile of landing slack);
// the compiler schedules ds_reads/MFMA with fine-grained lgkmcnt.
// ---------------------------------------------------------------------------
__global__ __launch_bounds__(512, 2)
void sim_gemm(const ushort* __restrict__ ws_a, const ushort* __restrict__ ws_b,
              unsigned* __restrict__ cand)
{
    __shared__ __align__(16) char pool[131072];

    const int id = blockIdx.x;
    const int cc = (id & 7) + ((id >> 5) << 3);   // col-chunk 0..391
    const int rc = (id >> 3) & 3;                 // row-chunk 0..3

    const int t    = threadIdx.x;
    const int wid  = t >> 6, lane = t & 63;
    const int wm   = wid >> 2, wn = wid & 3;
    const int l16  = lane & 15, lk = lane >> 4;

    auto stage_slot = [&](int kt, int slot, int buf) {
        char* ldst = pool + buf*65536 + slot*1024;
        const ushort* src;
        if (slot < 32) {
            src = ws_a + (((size_t)(kt*2 + (slot>>4))*64) + rc*16 + (slot & 15))*512
                       + (size_t)lane*8;
        } else {
            int s2 = slot - 32;
            src = ws_b + (((size_t)(kt*2 + (s2>>4))*NCB_B) + cc*16 + (s2 & 15))*512
                       + (size_t)lane*8;
        }
        GL2LDS(src, (ushort*)ldst);
    };

    f32x4 acc[8][4] = {};

    // prologue: stage K-tile 0 into buffer 0, drain, barrier
    #pragma unroll
    for (int j = 0; j < 8; ++j) stage_slot(0, wid*8 + j, 0);
    asm volatile("s_waitcnt vmcnt(0)" ::: "memory");
    __builtin_amdgcn_s_barrier();
    asm volatile("" ::: "memory");

    for (int kt = 0; kt < 5; ++kt) {
        const int buf = kt & 1;
        const ushort* Ab = (const ushort*)(pool + buf*65536);
        const ushort* Bb = (const ushort*)(pool + buf*65536 + 32768);

        // stage the whole next K-tile now: a full K-tile of landing slack
        if (kt < 4) {
            #pragma unroll
            for (int j = 0; j < 8; ++j)
                stage_slot(kt + 1, wid*8 + j, buf ^ 1);
        }

        // B fragments once per K-tile
        bf16x8 bfr[2][4];
        #pragma unroll
        for (int kb = 0; kb < 2; ++kb)
            #pragma unroll
            for (int nf = 0; nf < 4; ++nf)
                bfr[kb][nf] = *reinterpret_cast<const bf16x8*>(
                    Bb + (size_t)(kb*16 + wn*4 + nf)*512 + lane*8);

        // 4 row-pair groups; no intra-K-tile barriers
        #pragma unroll
        for (int p = 0; p < 4; ++p) {
            bf16x8 af[2][2];
            #pragma unroll
            for (int kb = 0; kb < 2; ++kb)
                #pragma unroll
                for (int m2 = 0; m2 < 2; ++m2)
                    af[kb][m2] = *reinterpret_cast<const bf16x8*>(
                        Ab + (size_t)(kb*16 + wm*8 + p*2 + m2)*512 + lane*8);

            __builtin_amdgcn_s_setprio(1);
            #pragma unroll
            for (int m2 = 0; m2 < 2; ++m2)
                #pragma unroll
                for (int nf = 0; nf < 4; ++nf) {
                    acc[p*2+m2][nf] = __builtin_amdgcn_mfma_f32_16x16x32_bf16(
                        bfr[0][nf], af[0][m2], acc[p*2+m2][nf], 0, 0, 0);
                    acc[p*2+m2][nf] = __builtin_amdgcn_mfma_f32_16x16x32_bf16(
                        bfr[1][nf], af[1][m2], acc[p*2+m2][nf], 0, 0, 0);
                }
            __builtin_amdgcn_s_setprio(0);
        }

        // K-tile boundary: own stages drained, then publish to all waves
        if (kt < 4) {
            asm volatile("s_waitcnt vmcnt(0)" ::: "memory");
            __builtin_amdgcn_s_barrier();
            asm volatile("" ::: "memory");
        }
    }

    // --- epilogue: quad scan -> per-lane top2 -> LDS -> compress ---
    __syncthreads();   // all waves done reading pool before reuse
    int* Cls = (int*)pool;
    #pragma unroll
    for (int mf = 0; mf < 8; ++mf) {
        int k0 = 0, k1 = 0;
        #pragma unroll
        for (int nf = 0; nf < 4; ++nf) {
            float qm = fmaxf(fmaxf(acc[mf][nf][0], acc[mf][nf][1]),
                             fmaxf(acc[mf][nf][2], acc[mf][nf][3]));
            int key = (int)((__float_as_uint(qm) & 0xFFFF0000u)
                            | (unsigned)(wn*16 + nf*4 + lk));
            if (key > k0)      { k1 = k0; k0 = key; }
            else if (key > k1) { k1 = key; }
        }
        int row = wm*128 + mf*16 + l16;
        int ent = wn*4 + lk;
        Cls[row*33 + ent*2 + 0] = k0;
        Cls[row*33 + ent*2 + 1] = k1;
    }
    __syncthreads();

    {
        int row  = t >> 1, half = t & 1;
        int ks[4] = {0, 0, 0, 0};
        #pragma unroll
        for (int j = 0; j < 16; ++j)
            ins4(ks, Cls[row*33 + half*16 + j]);
        int grow = rc*256 + row;
        size_t base = (size_t)grow*NCAND + cc*8 + half*4;
        *reinterpret_cast<uint4*>(&cand[base]) =
            make_uint4((unsigned)ks[0], (unsigned)ks[1],
                       (unsigned)ks[2], (unsigned)ks[3]);
    }
}

// ---------------------------------------------------------------------------
// Kernel 3a: wave-parallel exact top-24 per row. [unchanged from round 12]
// ---------------------------------------------------------------------------
__global__ __launch_bounds__(256, 8)
void merge_topq(const unsigned* __restrict__ cand, int* __restrict__ quads)
{
    __shared__ u64 Wv[4*NKF];

    const int row  = blockIdx.x;
    const int t    = threadIdx.x;
    const int wid  = t >> 6, lane = t & 63;

    u64 a[13];
    #pragma unroll
    for (int i = 0; i < 13; ++i) a[i] = 0ull;

    const unsigned* rc = cand + (size_t)row*NCAND;
    #pragma unroll
    for (int i = 0; i < 13; ++i) {
        int off = i*64 + lane;
        if (off < 784) {
            int c = wid*784 + off;
            unsigned e = rc[c];
            u64 comb = ((u64)(e ^ 0x80000000u) << 32)
                     | (unsigned)(((c >> 3) << 6) | (e & 63u));
            pins64<13>(a, comb);
        }
    }

    u64 mywin = 0ull;
    for (int k = 0; k < NKF; ++k) {
        u64 h = a[0], r = h;
        #pragma unroll
        for (int m = 1; m < 64; m <<= 1) {
            u64 o = __shfl_xor(r, m);
            r = (o > r) ? o : r;
        }
        bool win = (h == r);
        #pragma unroll
        for (int j = 0; j < 12; ++j) a[j] = win ? a[j+1] : a[j];
        a[12] = win ? 0ull : a[12];
        mywin = (lane == k) ? r : mywin;
    }
    if (lane < NKF) Wv[wid*NKF + lane] = mywin;
    __syncthreads();

    if (wid == 0) {
        u64 b0 = Wv[lane];
        u64 b1 = (lane < 32) ? Wv[lane + 64] : 0ull;
        if (b1 > b0) { u64 tmp = b0; b0 = b1; b1 = tmp; }

        u64 fin = 0ull;
        for (int k = 0; k < NKF; ++k) {
            u64 h = b0, r = h;
            #pragma unroll
            for (int m = 1; m < 64; m <<= 1) {
                u64 o = __shfl_xor(r, m);
                r = (o > r) ? o : r;
            }
            bool win = (h == r);
            b0 = win ? b1 : b0;
            b1 = win ? 0ull : b1;
            fin = (lane == k) ? r : fin;
        }
        if (lane < NKF) quads[row*NKF + lane] = (int)(fin & 0xffffffffull);
    }
}

// ---------------------------------------------------------------------------
// Kernel 3b: dense exact rescore. One 16-lane group per dot. [unchanged]
// ---------------------------------------------------------------------------
__global__ __launch_bounds__(256, 8)
void rescore_exact(const int* __restrict__ quads, const int* __restrict__ wordid,
                   const float* __restrict__ weight, double* __restrict__ scores)
{
    const int g = (blockIdx.x * 256 + threadIdx.x) >> 4;
    const int l = threadIdx.x & 15;
    const int row = g / NDOT;
    const int ci  = g - row * NDOT;

    const int q   = quads[row*NKF + (ci >> 2)];
    const int col = q*4 + (ci & 3);
    const bool valid = (col < VOCAB);
    const int col_eff = valid ? col : 0;

    const float* qr = weight + (size_t)wordid[row]*KDIM;
    const float* wr = weight + (size_t)col_eff*KDIM;

    double a0 = 0.0, a1 = 0.0;
    #pragma unroll
    for (int k = 0; k < 4; ++k) {
        int sl = (l + 16*k) * 4;
        float4 qa = *reinterpret_cast<const float4*>(qr + sl);
        float4 wb = *reinterpret_cast<const float4*>(wr + sl);
        a0 += (double)qa.x * wb.x + (double)qa.z * wb.z;
        a1 += (double)qa.y * wb.y + (double)qa.w * wb.w;
    }
    if (l < 11) {
        int sl = (l + 64) * 4;
        float4 qa = *reinterpret_cast<const float4*>(qr + sl);
        float4 wb = *reinterpret_cast<const float4*>(wr + sl);
        a0 += (double)qa.x * wb.x + (double)qa.z * wb.z;
        a1 += (double)qa.y * wb.y + (double)qa.w * wb.w;
    }
    double a = a0 + a1;
    #pragma unroll
    for (int m = 1; m < 16; m <<= 1) a += __shfl_xor(a, m);

    if (l == 0) scores[g] = valid ? a : -1e300;
}

// ---------------------------------------------------------------------------
// Kernel 3c: per row, wave-parallel top-11 of the 96 exact scores. [unchanged]
// ---------------------------------------------------------------------------
__global__ __launch_bounds__(64, 8)
void final_select(const double* __restrict__ scores, const int* __restrict__ quads,
                  float* __restrict__ out)
{
    const int row  = blockIdx.x;
    const int lane = threadIdx.x;

    double v0 = -INFINITY, v1 = -INFINITY;
    int    c0 = 0x7fffffff, c1 = 0x7fffffff;
    if (lane < NDOT/2) {
        int i0 = lane*2, i1 = lane*2 + 1;
        v0 = scores[(size_t)row*NDOT + i0];
        v1 = scores[(size_t)row*NDOT + i1];
        c0 = quads[row*NKF + (i0 >> 2)]*4 + (i0 & 3);
        c1 = quads[row*NKF + (i1 >> 2)]*4 + (i1 & 3);
    }

    for (int kk = 0; kk < TOPK + 1; ++kk) {
        bool sel = (v0 > v1) || (v0 == v1 && c0 < c1);
        double bv = sel ? v0 : v1;
        int    bc = sel ? c0 : c1;
        #pragma unroll
        for (int m = 1; m < 64; m <<= 1) {
            double ov = __shfl_xor(bv, m);
            int    oc = __shfl_xor(bc, m);
            if (ov > bv || (ov == bv && oc < bc)) { bv = ov; bc = oc; }
        }
        if (kk >= 1 && lane == 0) {
            out[(size_t)row*TOPK + (kk-1)] = (float)bv;
            out[(size_t)BATCH*TOPK + (size_t)row*TOPK + (kk-1)] = (float)bc;
        }
        if (c0 == bc) v0 = -INFINITY;
        if (c1 == bc) v1 = -INFINITY;
    }
}

extern "C" void kernel_launch(void* const* d_in, const int* in_sizes, int n_in,
                              void* d_out, int out_size, void* d_ws, size_t ws_size,
                              hipStream_t stream) {
    const int*   wordid = (const int*)d_in[0];
    const float* weight = (const float*)d_in[1];
    float* out = (float*)d_out;

    const size_t SZ_B = (size_t)NCB_B * NKB * 64 * 16;   // 64,225,280 B
    const size_t SZ_A = (size_t)NCB_A * NKB * 64 * 16;   //    655,360 B

    char* p = (char*)d_ws;
    ushort*   ws_b = (ushort*)p;  p += SZ_B;
    ushort*   ws_a = (ushort*)p;  p += SZ_A;
    unsigned* cand = (unsigned*)p;

    int*    quads  = (int*)ws_a;      // ws_a dead after sim_gemm
    double* scores = (double*)cand;   // cand dead after merge_topq

    convert_frags<<<NCB_B/4 + NCB_A/4, 256, 0, stream>>>(wordid, weight, ws_b, ws_a, NCB_B/4);
    sim_gemm<<<NCC*4, 512, 0, stream>>>(ws_a, ws_b, cand);
    merge_topq<<<BATCH, 256, 0, stream>>>(cand, quads);
    rescore_exact<<<(BATCH*NDOT)/16, 256, 0, stream>>>(quads, wordid, weight, scores);
    final_select<<<BATCH, 64, 0, stream>>>(scores, quads, out);
}